// Round 8
// baseline (15275.418 us; speedup 1.0000x reference)
//
#include <hip/hip_runtime.h>
#include <hip/hip_bf16.h>
#include <stdint.h>
#include <stddef.h>

// Problem dims
#define SEQ   2048
#define BATCH 32
#define HID   512
#define G4    2048   // 4*HID
#define NWG   16     // workgroups per direction (one XCD engine)
#define UE    32     // hidden units per WG (NWG*UE == HID)
#define RING  8      // hbuf ring depth (slots stay L2-hot)

typedef __bf16 bf16;
typedef bf16     bf16x8 __attribute__((ext_vector_type(8)));
typedef float    f32x4  __attribute__((ext_vector_type(4)));
typedef unsigned u32x4v __attribute__((ext_vector_type(4)));

// sc0 loads: bypass L1, served by the XCD's L2 (valid for same-XCD producer
// stores, which land in L2 via write-back). NOT valid cross-XCD — engine
// construction guarantees all peers share one XCD.
__device__ __forceinline__ uint32_t ld_sc0_u32(const volatile uint32_t* p) {
    uint32_t v;
    asm volatile("global_load_dword %0, %1, off sc0\n\ts_waitcnt vmcnt(0)"
                 : "=v"(v) : "v"(p) : "memory");
    return v;
}
__device__ __forceinline__ u32x4v ld_sc0_b128(const void* p) {
    u32x4v v;
    asm volatile("global_load_dwordx4 %0, %1, off sc0"
                 : "=v"(v) : "v"(p) : "memory");
    return v;
}

// ---------------------------------------------------------------------------
// Prep 1: embedding gather -> bf16 [S*B][H]
// ---------------------------------------------------------------------------
__global__ void k_embed(const int* __restrict__ tokens,
                        const float* __restrict__ table,
                        bf16* __restrict__ embT)
{
    int wid  = (blockIdx.x * blockDim.x + threadIdx.x) >> 6;
    int lane = threadIdx.x & 63;
    int k = lane * 8;                      // 64 lanes * 8 = 512 = HID
    if (wid < SEQ * BATCH) {
        int tok = tokens[wid];
        const float* src = table + (size_t)tok * HID;
        float4 a = *(const float4*)(src + k);
        float4 b = *(const float4*)(src + k + 4);
        bf16x8 v;
        v[0]=(bf16)a.x; v[1]=(bf16)a.y; v[2]=(bf16)a.z; v[3]=(bf16)a.w;
        v[4]=(bf16)b.x; v[5]=(bf16)b.y; v[6]=(bf16)b.z; v[7]=(bf16)b.w;
        *(bf16x8*)(embT + (size_t)wid * HID + k) = v;
    }
}

// ---------------------------------------------------------------------------
// Prep 2: transpose+convert weights: [HID][G4] fp32 -> [G4][HID] bf16
// ---------------------------------------------------------------------------
__global__ void k_transpose(const float* s0, const float* s1,
                            const float* s2, const float* s3,
                            bf16* __restrict__ dst)
{
    const float* srcs[4] = {s0, s1, s2, s3};
    const float* src = srcs[blockIdx.y];
    bf16* d = dst + (size_t)blockIdx.y * ((size_t)G4 * HID);
    int c = blockIdx.x * 256 + threadIdx.x;          // 8 blocks * 256 = 2048
    for (int k = 0; k < HID; k++)                    // coalesced reads over c
        d[(size_t)c * HID + k] = (bf16)src[(size_t)k * G4 + c];
}

// ---------------------------------------------------------------------------
// Persistent bidirectional LSTM — XCD-LOCAL ENGINES.
// 256 WGs launched (1/CU by LDS). Each WG reads its physical XCD
// (HW_REG_XCC_ID), claims a rank on a per-XCD counter; rank-0 WGs elect one
// even-parity XCD (forward engine) and one odd (backward) via CAS. The 16
// lowest-rank WGs on an elected XCD run that direction; everyone else exits.
// All recurrence sync is intra-XCD through the local L2: plain write-back
// stores + __syncthreads (vmcnt drain) + plain flag store on the producer;
// sc0 (L1-bypass) loads on the consumer. ~300cy per leg vs ~2000cy at LLC.
// Per WG: 32 units (128 gate cols); whT slice 128KB LDS-resident.
// LDS: [0,128K) whT swizzled rows [128 cols][512 k]; [128K,+16.9K) gbuf.
// hbuf: [slot][HID/8 kblk][BATCH][8] bf16 -> MFMA A-fragment = 16B contig.
// ---------------------------------------------------------------------------
__global__ __launch_bounds__(256, 1) void k_lstm(
    const bf16* __restrict__ embT,
    const bf16* __restrict__ wxT,    // [2][G4][HID] bf16
    const bf16* __restrict__ whT,    // [2][G4][HID] bf16
    const float* __restrict__ bx_f, const float* __restrict__ bh_f,
    const float* __restrict__ bx_b, const float* __restrict__ bh_b,
    const float* __restrict__ h0,
    bf16* __restrict__ hbuf_f, bf16* __restrict__ hbuf_b,
    int* __restrict__ ectl,          // [8] xcd rank counters, [8..9] elect
    uint32_t* __restrict__ flags,    // [2][16] padded 128B
    float* __restrict__ out)
{
    __shared__ __align__(16) char smem[131072 + 16896];
    float* gbuf = (float*)(smem + 131072);   // [32][132] fp32

    const int tid = threadIdx.x;

    // ---- XCD discovery + engine election ----
    int xcd;
    asm volatile("s_getreg_b32 %0, hwreg(HW_REG_XCC_ID)" : "=s"(xcd));
    __shared__ int sctl[2];
    if (tid == 0) {
        int rank = __hip_atomic_fetch_add(&ectl[xcd], 1, __ATOMIC_RELAXED,
                                          __HIP_MEMORY_SCOPE_AGENT);
        int par = xcd & 1;
        if (rank == 0) {
            int expd = 0;
            __hip_atomic_compare_exchange_strong(&ectl[8 + par], &expd, xcd + 1,
                __ATOMIC_RELAXED, __ATOMIC_RELAXED, __HIP_MEMORY_SCOPE_AGENT);
        }
        int e = 0;
        uint64_t t0 = __builtin_amdgcn_s_memrealtime();
        for (;;) {
            e = __hip_atomic_load(&ectl[8 + par], __ATOMIC_RELAXED,
                                  __HIP_MEMORY_SCOPE_AGENT);
            if (e) break;
            if (__builtin_amdgcn_s_memrealtime() - t0 > 100000ULL) break; // 1ms
            __builtin_amdgcn_s_sleep(8);
        }
        sctl[0] = rank; sctl[1] = e;
    }
    __syncthreads();
    const int  rank   = sctl[0];
    const bool is_eng = (sctl[1] == xcd + 1) && (rank < NWG);
    if (!is_eng) return;
    const int dir = xcd & 1;
    const int g   = rank;                  // engine slice [g*32, g*32+32)

    const bf16* wxTs = wxT + (size_t)dir * ((size_t)G4 * HID);
    const bf16* whTs = whT + (size_t)dir * ((size_t)G4 * HID);
    const float* bx  = dir ? bx_b : bx_f;
    const float* bh  = dir ? bh_b : bh_f;
    bf16* hbuf       = dir ? hbuf_b : hbuf_f;
    volatile uint32_t* myflag = flags + dir * 512 + g * 32;
    const uint32_t* fbase     = flags + dir * 512;

    // ---- load whT slice into LDS: rows = 128 local gate cols, swizzled ----
    // local col c -> global gate row = (c>>5)*HID + g*32 + (c&31)
    #pragma unroll
    for (int i = 0; i < 32; i++) {
        int e  = i * 2048 + tid * 8;       // elem in [0,65536)
        int lc = e >> 9;                   // 0..127
        int k  = e & 511;
        int grow = (lc >> 5) * HID + g * UE + (lc & 31);
        bf16x8 v = *(const bf16x8*)(whTs + (size_t)grow * HID + k);
        *(bf16x8*)(smem + lc * 1024 + ((k * 2) ^ ((lc & 7) << 4))) = v;
    }

    // wave/tile assignment: 4 waves = 2 M-tiles x 2 N-groups (4 Ntiles each)
    const int w     = tid >> 6;
    const int lane  = tid & 63;
    const int mtile = w >> 1;              // batch tile 0..1
    const int ng    = w & 1;               // N-group 0..1 (cols ng*64..+64)
    const int lrow  = lane & 15;
    const int lq    = lane >> 4;           // k-quad 0..3
    const int arow  = mtile * 16 + lrow;   // A rows (batch)

    // per-Ntile constants
    float bias_nt[4];
    const bf16* bXp[4];
    #pragma unroll
    for (int nt = 0; nt < 4; nt++) {
        int lcb  = ng * 64 + nt * 16 + lrow;            // local col 0..127
        int gcol = (lcb >> 5) * HID + g * UE + (lcb & 31);
        bias_nt[nt] = bx[gcol] + bh[gcol];
        bXp[nt] = wxTs + (size_t)gcol * HID + lq * 8;
    }
    const int b0off = (ng * 64 + lrow) * 1024;          // LDS B row base
    const int bswz  = (lrow & 7) << 4;

    // pointwise: all 256 threads, 4 units each
    const int pb = tid >> 3;               // batch 0..31
    const int pu = (tid & 7) << 2;         // unit offset {0,4,...,28}
    const int kbblk = g * 4 + (pu >> 3);   // hbuf k-block for owned units

    // creg = c0 = h0; also stage h0 (bf16) into ring slot 0
    f32x4 creg = *(const f32x4*)(h0 + (size_t)pb * HID + g * UE + pu);
    {
        union { bf16 h[4]; unsigned long long q; } pk;
        #pragma unroll
        for (int j = 0; j < 4; j++) pk.h[j] = (bf16)creg[j];
        *(volatile unsigned long long*)(hbuf + (size_t)(kbblk * 32 + pb) * 8
                                        + (pu & 7)) = pk.q;
    }
    __syncthreads();                       // drains LDS + h0 stores (vmcnt 0)
    if (tid == 0) *myflag = 1;             // h_0 ready

    for (int t = 0; t < SEQ; t++) {
        const int s = dir ? (SEQ - 1 - t) : t;

        // ---- phase X: acc = bias + emb[s] @ wx (streamed, L2-hot) ----
        f32x4 acc[4];
        #pragma unroll
        for (int nt = 0; nt < 4; nt++)
            acc[nt] = f32x4{bias_nt[nt], bias_nt[nt], bias_nt[nt], bias_nt[nt]};
        const bf16* aXp = embT + ((size_t)s * BATCH + arow) * HID + lq * 8;
        #pragma unroll
        for (int kk = 0; kk < 16; kk++) {
            bf16x8 a = *(const bf16x8*)(aXp + kk * 32);
            #pragma unroll
            for (int nt = 0; nt < 4; nt++) {
                bf16x8 b = *(const bf16x8*)(bXp[nt] + kk * 32);
                acc[nt] = __builtin_amdgcn_mfma_f32_16x16x32_bf16(a, b, acc[nt], 0, 0, 0);
            }
        }

        // ---- gate: every wave polls the 16 engine flags via L2 (sc0) ----
        {
            const uint32_t* fp = fbase + (lane & 15) * 32;
            int rounds = 0;
            uint64_t t0c = 0;
            for (;;) {
                uint32_t v = ld_sc0_u32(fp);
                if (__all(v >= (uint32_t)(t + 1))) break;
                if (!(++rounds & 63)) {        // hang safety ~100us
                    uint64_t now = __builtin_amdgcn_s_memrealtime();
                    if (!t0c) t0c = now;
                    else if (now - t0c > 10000ULL) break;
                }
            }
        }

        // ---- phase H: A-fragments sc0 from ring slot t&7, B from LDS ----
        {
            const char* hb = (const char*)hbuf + (size_t)(t & (RING - 1)) * 32768
                             + ((lq * 32 + arow) << 4);
            u32x4v hA[16];
            #pragma unroll
            for (int kk = 0; kk < 16; kk++)
                hA[kk] = ld_sc0_b128(hb + kk * 2048);
            asm volatile("s_waitcnt vmcnt(0)" ::: "memory");
            __builtin_amdgcn_sched_barrier(0);
            #pragma unroll
            for (int kk = 0; kk < 16; kk++) {
                union { u32x4v u; bf16x8 v; } ua;
                ua.u = hA[kk];
                const int kb = kk * 64 + (lq << 4);
                #pragma unroll
                for (int nt = 0; nt < 4; nt++) {
                    bf16x8 b = *(const bf16x8*)(smem + b0off + nt * 16384 + (kb ^ bswz));
                    acc[nt] = __builtin_amdgcn_mfma_f32_16x16x32_bf16(ua.v, b, acc[nt], 0, 0, 0);
                }
            }
        }

        // ---- gates -> gbuf (C/D: col = lane&15, row = lq*4 + r) ----
        {
            const int r0 = mtile * 16 + lq * 4;
            #pragma unroll
            for (int nt = 0; nt < 4; nt++) {
                const int lc = ng * 64 + nt * 16 + lrow;
                #pragma unroll
                for (int r = 0; r < 4; r++)
                    gbuf[(r0 + r) * 132 + lc] = acc[nt][r];
            }
        }
        __syncthreads();   // barB: gbuf ready

        // ---- pointwise LSTM cell: all 256 threads, 4 units each ----
        {
            f32x4 gi = *(const f32x4*)(gbuf + pb * 132 + pu);
            f32x4 gf = *(const f32x4*)(gbuf + pb * 132 + 32 + pu);
            f32x4 gg = *(const f32x4*)(gbuf + pb * 132 + 64 + pu);
            f32x4 go = *(const f32x4*)(gbuf + pb * 132 + 96 + pu);
            float hv[4];
            #pragma unroll
            for (int j = 0; j < 4; j++) {
                float si = 1.f / (1.f + __expf(-gi[j]));
                float sf = 1.f / (1.f + __expf(-gf[j]));
                float so = 1.f / (1.f + __expf(-go[j]));
                float e2 = __expf(2.f * gg[j]);
                float tg = (e2 - 1.f) / (e2 + 1.f);
                creg[j] = sf * creg[j] + si * tg;
                float ec = __expf(2.f * creg[j]);
                float tc = (ec - 1.f) / (ec + 1.f);
                hv[j] = so * tc;
            }
            // h_{t+1} -> ring slot (t+1)&7: plain write-back store (L2-local)
            union { bf16 h[4]; unsigned long long q; } pk;
            #pragma unroll
            for (int j = 0; j < 4; j++) pk.h[j] = (bf16)hv[j];
            *(volatile unsigned long long*)(hbuf
                + (size_t)((t + 1) & (RING - 1)) * 16384
                + (size_t)(kbblk * 32 + pb) * 8 + (pu & 7)) = pk.q;
            __syncthreads();   // drains vmcnt(0) -> h stores in L2; barrier
            if (tid == 0) *myflag = (uint32_t)(t + 2);   // h_{t+1} ready
            // out store, nontemporal (HBM stream, off critical path)
            f32x4 ov = {hv[0], hv[1], hv[2], hv[3]};
            __builtin_nontemporal_store(ov,
                (f32x4*)(out + (size_t)pb * ((size_t)SEQ * 2 * HID)
                         + (size_t)s * (2 * HID) + dir * HID + g * UE + pu));
        }
        // gbuf WAR across steps is ordered transitively: next-step gbuf
        // writes require the poll to see own flag >= t+2, which is stored
        // only after the post-pointwise barrier (all gbuf reads done).
    }
}

// ---------------------------------------------------------------------------
// Workspace layout (bytes):
//   embT   :         0 ..  67,108,864   bf16 [S*B][H]
//   hbuf_f :  67,108,864 .. +262,144    bf16 ring [8][64 kblk][32 b][8]
//   hbuf_b :  67,371,008 .. +262,144
//   wxT    :  67,633,152 .. +4,194,304  bf16 [2][G4][H]
//   whT    :  71,827,456 .. +4,194,304
//   ctl    :  76,021,760 .. +128        cnt[8] + elect[2] (zeroed/launch)
//   flags  :  76,021,888 .. +4,096      2 x 16 x 128B padded (zeroed/launch)
// ---------------------------------------------------------------------------
extern "C" void kernel_launch(void* const* d_in, const int* in_sizes, int n_in,
                              void* d_out, int out_size, void* d_ws, size_t ws_size,
                              hipStream_t stream)
{
    const int*   tokens = (const int*)  d_in[0];
    const float* h0     = (const float*)d_in[1];
    const float* table  = (const float*)d_in[2];
    const float* wx_f   = (const float*)d_in[3];
    const float* bx_f   = (const float*)d_in[4];
    const float* wh_f   = (const float*)d_in[5];
    const float* bh_f   = (const float*)d_in[6];
    const float* wx_b   = (const float*)d_in[7];
    const float* bx_b   = (const float*)d_in[8];
    const float* wh_b   = (const float*)d_in[9];
    const float* bh_b   = (const float*)d_in[10];
    float* out = (float*)d_out;
    char*  ws  = (char*)d_ws;

    const size_t OFF_EMBT  = 0;
    const size_t OFF_HF    = 67108864ULL;
    const size_t OFF_HB    = OFF_HF  + 262144ULL;
    const size_t OFF_WXT   = OFF_HB  + 262144ULL;
    const size_t OFF_WHT   = OFF_WXT + 4194304ULL;
    const size_t OFF_CTL   = OFF_WHT + 4194304ULL;
    const size_t OFF_FLAGS = OFF_CTL + 128ULL;

    bf16* embT   = (bf16*)(ws + OFF_EMBT);
    bf16* hbuf_f = (bf16*)(ws + OFF_HF);
    bf16* hbuf_b = (bf16*)(ws + OFF_HB);
    bf16* wxT    = (bf16*)(ws + OFF_WXT);
    bf16* whT    = (bf16*)(ws + OFF_WHT);
    int*      ectl  = (int*)(ws + OFF_CTL);
    uint32_t* flags = (uint32_t*)(ws + OFF_FLAGS);

    // election state + flags must start at 0 every launch
    (void)hipMemsetAsync(ws + OFF_CTL, 0, 128 + 4096, stream);

    // embedding gather
    {
        int blocks = (SEQ * BATCH * 64) / 256;
        k_embed<<<blocks, 256, 0, stream>>>(tokens, table, embT);
    }
    // weight transposes: slots {wxT_f, wxT_b, whT_f, whT_b} contiguous
    k_transpose<<<dim3(8, 4), 256, 0, stream>>>(wx_f, wx_b, wh_f, wh_b, wxT);

    // persistent recurrence: 256 WGs (1/CU); 2 x 16 become XCD-local engines
    k_lstm<<<256, 256, 0, stream>>>(embT, wxT, whT,
                                    bx_f, bh_f, bx_b, bh_b, h0,
                                    hbuf_f, hbuf_b, ectl, flags, out);
}